// Round 2
// baseline (610.497 us; speedup 1.0000x reference)
//
#include <hip/hip_runtime.h>

// Problem constants (fixed by the reference)
constexpr int Bn = 4, Nn = 5000, Kd = 20, Hh = 128;
constexpr int Ee = Nn * Kd;  // 100000

typedef __attribute__((ext_vector_type(8))) short bf16x8;
typedef __attribute__((ext_vector_type(4))) float f32x4;

__device__ __forceinline__ short f2bf(float f) {
  unsigned int u = __builtin_bit_cast(unsigned int, f);
  u += 0x7fffu + ((u >> 16) & 1u);  // RNE (finite inputs only)
  return (short)(u >> 16);
}

__device__ __forceinline__ bf16x8 cvt8(const float* __restrict__ p) {
  float4 lo = *reinterpret_cast<const float4*>(p);
  float4 hi = *reinterpret_cast<const float4*>(p + 4);
  bf16x8 r;
  r[0] = f2bf(lo.x); r[1] = f2bf(lo.y); r[2] = f2bf(lo.z); r[3] = f2bf(lo.w);
  r[4] = f2bf(hi.x); r[5] = f2bf(hi.y); r[6] = f2bf(hi.z); r[7] = f2bf(hi.w);
  return r;
}

__device__ __forceinline__ bf16x8 zero8() {
  bf16x8 r;
  #pragma unroll
  for (int i = 0; i < 8; ++i) r[i] = 0;
  return r;
}

// ---------------------------------------------------------------------------
// Kernel 0: convert weights to bf16, build fused bias vectors.
// ---------------------------------------------------------------------------
__global__ void __launch_bounds__(256) prep_kernel(
    const float* __restrict__ U_w, const float* __restrict__ iU_w,
    const float* __restrict__ Vf_w, const float* __restrict__ Vt_w,
    const float* __restrict__ U_b, const float* __restrict__ iU_b,
    const float* __restrict__ W_ph,
    short* __restrict__ Ubf, short* __restrict__ iUbf,
    short* __restrict__ Vfbf, short* __restrict__ Vtbf,
    float* __restrict__ biasA, float* __restrict__ biasB) {
  int t = blockIdx.x * blockDim.x + threadIdx.x;
  if (t < Hh * Hh) {
    Ubf[t]  = f2bf(U_w[t]);
    iUbf[t] = f2bf(iU_w[t]);
    Vfbf[t] = f2bf(Vf_w[t]);
    Vtbf[t] = f2bf(Vt_w[t]);
  }
  if (t < Hh) {
    biasA[t] = U_b[t] + iU_b[t];
    biasB[t] = U_b[t] + W_ph[t];
  }
}

// ---------------------------------------------------------------------------
// Kernel 1: Vx_from = x @ Vf_w^T + b, Vx_to = x @ Vt_w^T + b.
// ---------------------------------------------------------------------------
__global__ void __launch_bounds__(256) vxproj_kernel(
    const float* __restrict__ x,
    const short* __restrict__ Vfbf, const short* __restrict__ Vtbf,
    const float* __restrict__ Vf_b, const float* __restrict__ Vt_b,
    float* __restrict__ VxF, float* __restrict__ VxT) {
  int wave = (int)((blockIdx.x * blockDim.x + threadIdx.x) >> 6);
  constexpr int NW = (Bn * Nn) / 16;  // 1250
  if (wave >= NW) return;
  int lane = threadIdx.x & 63;
  int r = lane & 15, kg = lane >> 4;
  int row0 = wave * 16;
  const float* xrow = x + (size_t)(row0 + r) * Hh;

  f32x4 accF[8], accT[8];
  #pragma unroll
  for (int ht = 0; ht < 8; ++ht) {
    accF[ht] = (f32x4)(0.0f);
    accT[ht] = (f32x4)(0.0f);
  }

  #pragma unroll
  for (int kk = 0; kk < 4; ++kk) {
    int k0 = kk * 32 + kg * 8;
    bf16x8 a = cvt8(xrow + k0);
    #pragma unroll
    for (int ht = 0; ht < 8; ++ht) {
      bf16x8 bF = *reinterpret_cast<const bf16x8*>(Vfbf + (ht * 16 + r) * Hh + k0);
      bf16x8 bT = *reinterpret_cast<const bf16x8*>(Vtbf + (ht * 16 + r) * Hh + k0);
      accF[ht] = __builtin_amdgcn_mfma_f32_16x16x32_bf16(a, bF, accF[ht], 0, 0, 0);
      accT[ht] = __builtin_amdgcn_mfma_f32_16x16x32_bf16(a, bT, accT[ht], 0, 0, 0);
    }
  }

  #pragma unroll
  for (int ht = 0; ht < 8; ++ht) {
    int h = ht * 16 + r;
    float bf = Vf_b[h], bt = Vt_b[h];
    #pragma unroll
    for (int i = 0; i < 4; ++i) {
      size_t row = (size_t)(row0 + kg * 4 + i);
      VxF[row * Hh + h] = accF[ht][i] + bf;
      VxT[row * Hh + h] = accT[ht][i] + bt;
    }
  }
}

// ---------------------------------------------------------------------------
// Kernel 2: main per-edge kernel (v2).
//   A = weight rows (from swizzled LDS), B = e rows (global fp32 -> bf16),
//   D: col = edge, row = h  =>  vectorized f32x4 epilogue.
// One wave = 32 edges (2 col-tiles of 16) x 128 h. 16 waves/block.
// ---------------------------------------------------------------------------
__global__ void __launch_bounds__(1024, 8) edge_kernel(
    const float* __restrict__ e,
    const int* __restrict__ edge_index,
    const int* __restrict__ inv_edge_index,
    const short* __restrict__ Ubf, const short* __restrict__ iUbf,
    const float* __restrict__ biasA, const float* __restrict__ biasB,
    const float* __restrict__ VxF, const float* __restrict__ VxT,
    float* __restrict__ out) {
  // ---- stage U, iU into LDS, XOR-swizzled: byte ^= (h&7)<<4 within row ----
  __shared__ short wlds[2 * Hh * Hh];  // 64 KiB
  #pragma unroll
  for (int cix = 0; cix < 4; ++cix) {
    const short* src = (cix < 2) ? Ubf : iUbf;
    int idx = (cix & 1) * 1024 + threadIdx.x;  // 16B-chunk id within matrix
    int h = idx >> 4, kb = idx & 15;           // row, 16B-slot in row
    bf16x8 v = *reinterpret_cast<const bf16x8*>(src + h * Hh + kb * 8);
    int dst = (cix >> 1) * (Hh * Hh) + h * Hh + (((kb * 16) ^ ((h & 7) << 4)) >> 1);
    *reinterpret_cast<bf16x8*>(wlds + dst) = v;
  }
  __syncthreads();

  int wv = (int)((blockIdx.x * blockDim.x + threadIdx.x) >> 6);
  if (wv >= Bn * (Ee / 32)) return;  // after barrier: safe
  int lane = threadIdx.x & 63;
  int c = lane & 15, kg = lane >> 4;
  constexpr int WPB = Ee / 32;  // 3125
  int b = wv / WPB;
  int j0 = (wv % WPB) * 32;
  const size_t ebase = (size_t)b * Ee;
  const float* ebat = e + ebase * Hh;

  // per-lane edge indices (et = 0,1)
  int jc[2] = {j0 + c, j0 + 16 + c};
  int i2[2], ei[2];
  bool ph[2];
  #pragma unroll
  for (int et = 0; et < 2; ++et) {
    i2[et] = inv_edge_index[ebase + jc[et]];
    ei[et] = edge_index[ebase + jc[et]];
    ph[et] = (i2[et] == Ee);
  }

  // load e rows (coalesced j, gathered idx2), convert to bf16 B-fragments
  bf16x8 a1[2][4], a2[2][4];
  #pragma unroll
  for (int et = 0; et < 2; ++et) {
    int row2 = ph[et] ? 0 : i2[et];
    #pragma unroll
    for (int kk = 0; kk < 4; ++kk) {
      int k0 = kk * 32 + kg * 8;
      a1[et][kk] = cvt8(ebat + (size_t)jc[et] * Hh + k0);
      bf16x8 t = cvt8(ebat + (size_t)row2 * Hh + k0);
      a2[et][kk] = ph[et] ? zero8() : t;
    }
  }

  f32x4 acc[2][8];
  #pragma unroll
  for (int et = 0; et < 2; ++et)
    #pragma unroll
    for (int ht = 0; ht < 8; ++ht) acc[et][ht] = (f32x4)(0.0f);

  // MFMA: A = W rows from LDS (row = ht*16 + c), B = e fragment
  #pragma unroll
  for (int kk = 0; kk < 4; ++kk) {
    #pragma unroll
    for (int ht = 0; ht < 8; ++ht) {
      int h = ht * 16 + c;
      int off = h * Hh + (((kk * 64 + kg * 16) ^ ((h & 7) << 4)) >> 1);
      bf16x8 wu = *reinterpret_cast<const bf16x8*>(wlds + off);
      bf16x8 wi = *reinterpret_cast<const bf16x8*>(wlds + Hh * Hh + off);
      #pragma unroll
      for (int et = 0; et < 2; ++et) {
        acc[et][ht] = __builtin_amdgcn_mfma_f32_16x16x32_bf16(wu, a1[et][kk], acc[et][ht], 0, 0, 0);
        acc[et][ht] = __builtin_amdgcn_mfma_f32_16x16x32_bf16(wi, a2[et][kk], acc[et][ht], 0, 0, 0);
      }
    }
  }

  // Epilogue: D col = edge (lane&15), row = h = ht*16 + kg*4 + i
  #pragma unroll
  for (int et = 0; et < 2; ++et) {
    const float* vt = VxT + ((size_t)b * Nn + ei[et]) * Hh;
    const float* vf = VxF + ((size_t)b * Nn + jc[et] / Kd) * Hh;
    float* orow = out + (ebase + (size_t)jc[et]) * Hh;
    #pragma unroll
    for (int ht = 0; ht < 8; ++ht) {
      int h0 = ht * 16 + kg * 4;
      f32x4 bA = *reinterpret_cast<const f32x4*>(biasA + h0);
      f32x4 bB = *reinterpret_cast<const f32x4*>(biasB + h0);
      f32x4 vt4 = *reinterpret_cast<const f32x4*>(vt + h0);
      f32x4 vf4 = *reinterpret_cast<const f32x4*>(vf + h0);
      f32x4 r = acc[et][ht] + (ph[et] ? bB : bA) + vt4 + vf4;
      *reinterpret_cast<f32x4*>(orow + h0) = r;
    }
  }
}

extern "C" void kernel_launch(void* const* d_in, const int* in_sizes, int n_in,
                              void* d_out, int out_size, void* d_ws, size_t ws_size,
                              hipStream_t stream) {
  const float* x   = (const float*)d_in[0];
  const float* e   = (const float*)d_in[1];
  const int* edge_index = (const int*)d_in[2];
  const int* inv_edge_index = (const int*)d_in[3];
  const float* U_w  = (const float*)d_in[4];
  const float* U_b  = (const float*)d_in[5];
  const float* Vf_w = (const float*)d_in[6];
  const float* Vf_b = (const float*)d_in[7];
  const float* Vt_w = (const float*)d_in[8];
  const float* Vt_b = (const float*)d_in[9];
  const float* iU_w = (const float*)d_in[10];
  const float* iU_b = (const float*)d_in[11];
  const float* W_ph = (const float*)d_in[12];
  float* out = (float*)d_out;

  // Workspace layout
  float* VxF   = (float*)d_ws;                         // B*N*H floats
  float* VxT   = VxF + (size_t)Bn * Nn * Hh;           // B*N*H floats
  float* biasA = VxT + (size_t)Bn * Nn * Hh;           // 128
  float* biasB = biasA + Hh;                           // 128
  short* Ubf   = (short*)(biasB + Hh);                 // 16384 shorts
  short* iUbf  = Ubf + Hh * Hh;
  short* Vfbf  = iUbf + Hh * Hh;
  short* Vtbf  = Vfbf + Hh * Hh;

  prep_kernel<<<dim3(64), dim3(256), 0, stream>>>(
      U_w, iU_w, Vf_w, Vt_w, U_b, iU_b, W_ph, Ubf, iUbf, Vfbf, Vtbf, biasA, biasB);

  vxproj_kernel<<<dim3(313), dim3(256), 0, stream>>>(
      x, Vfbf, Vtbf, Vf_b, Vt_b, VxF, VxT);

  int nwaves = Bn * (Ee / 32);                 // 12500
  int nblocks = (nwaves + 15) / 16;            // 782 blocks of 1024 threads
  edge_kernel<<<dim3(nblocks), dim3(1024), 0, stream>>>(
      e, edge_index, inv_edge_index, Ubf, iUbf, biasA, biasB, VxF, VxT, out);
}

// Round 3
// 214.064 us; speedup vs baseline: 2.8519x; 2.8519x over previous
//
#include <hip/hip_runtime.h>

// Problem constants (fixed by the reference)
constexpr int Bn = 4, Nn = 5000, Kd = 20, Hh = 128;
constexpr int Ee = Nn * Kd;  // 100000

typedef __attribute__((ext_vector_type(8))) short bf16x8;
typedef __attribute__((ext_vector_type(4))) float f32x4;

__device__ __forceinline__ short f2bf(float f) {
  unsigned int u = __builtin_bit_cast(unsigned int, f);
  u += 0x7fffu + ((u >> 16) & 1u);  // RNE (finite inputs only)
  return (short)(u >> 16);
}

__device__ __forceinline__ bf16x8 cvt8(const float* __restrict__ p) {
  float4 lo = *reinterpret_cast<const float4*>(p);
  float4 hi = *reinterpret_cast<const float4*>(p + 4);
  bf16x8 r;
  r[0] = f2bf(lo.x); r[1] = f2bf(lo.y); r[2] = f2bf(lo.z); r[3] = f2bf(lo.w);
  r[4] = f2bf(hi.x); r[5] = f2bf(hi.y); r[6] = f2bf(hi.z); r[7] = f2bf(hi.w);
  return r;
}

__device__ __forceinline__ bf16x8 zero8() {
  bf16x8 r;
  #pragma unroll
  for (int i = 0; i < 8; ++i) r[i] = 0;
  return r;
}

// ---------------------------------------------------------------------------
// Kernel 0: convert weights to bf16, build fused bias vectors.
// ---------------------------------------------------------------------------
__global__ void __launch_bounds__(256) prep_kernel(
    const float* __restrict__ U_w, const float* __restrict__ iU_w,
    const float* __restrict__ Vf_w, const float* __restrict__ Vt_w,
    const float* __restrict__ U_b, const float* __restrict__ iU_b,
    const float* __restrict__ W_ph,
    short* __restrict__ Ubf, short* __restrict__ iUbf,
    short* __restrict__ Vfbf, short* __restrict__ Vtbf,
    float* __restrict__ biasA, float* __restrict__ biasB) {
  int t = blockIdx.x * blockDim.x + threadIdx.x;
  if (t < Hh * Hh) {
    Ubf[t]  = f2bf(U_w[t]);
    iUbf[t] = f2bf(iU_w[t]);
    Vfbf[t] = f2bf(Vf_w[t]);
    Vtbf[t] = f2bf(Vt_w[t]);
  }
  if (t < Hh) {
    biasA[t] = U_b[t] + iU_b[t];
    biasB[t] = U_b[t] + W_ph[t];
  }
}

// ---------------------------------------------------------------------------
// Kernel 1: Vx_from = x @ Vf_w^T + b, Vx_to = x @ Vt_w^T + b.
// ---------------------------------------------------------------------------
__global__ void __launch_bounds__(256) vxproj_kernel(
    const float* __restrict__ x,
    const short* __restrict__ Vfbf, const short* __restrict__ Vtbf,
    const float* __restrict__ Vf_b, const float* __restrict__ Vt_b,
    float* __restrict__ VxF, float* __restrict__ VxT) {
  int wave = (int)((blockIdx.x * blockDim.x + threadIdx.x) >> 6);
  constexpr int NW = (Bn * Nn) / 16;  // 1250
  if (wave >= NW) return;
  int lane = threadIdx.x & 63;
  int r = lane & 15, kg = lane >> 4;
  int row0 = wave * 16;
  const float* xrow = x + (size_t)(row0 + r) * Hh;

  f32x4 accF[8], accT[8];
  #pragma unroll
  for (int ht = 0; ht < 8; ++ht) {
    accF[ht] = (f32x4)(0.0f);
    accT[ht] = (f32x4)(0.0f);
  }

  #pragma unroll
  for (int kk = 0; kk < 4; ++kk) {
    int k0 = kk * 32 + kg * 8;
    bf16x8 a = cvt8(xrow + k0);
    #pragma unroll
    for (int ht = 0; ht < 8; ++ht) {
      bf16x8 bF = *reinterpret_cast<const bf16x8*>(Vfbf + (ht * 16 + r) * Hh + k0);
      bf16x8 bT = *reinterpret_cast<const bf16x8*>(Vtbf + (ht * 16 + r) * Hh + k0);
      accF[ht] = __builtin_amdgcn_mfma_f32_16x16x32_bf16(a, bF, accF[ht], 0, 0, 0);
      accT[ht] = __builtin_amdgcn_mfma_f32_16x16x32_bf16(a, bT, accT[ht], 0, 0, 0);
    }
  }

  #pragma unroll
  for (int ht = 0; ht < 8; ++ht) {
    int h = ht * 16 + r;
    float bf = Vf_b[h], bt = Vt_b[h];
    #pragma unroll
    for (int i = 0; i < 4; ++i) {
      size_t row = (size_t)(row0 + kg * 4 + i);
      VxF[row * Hh + h] = accF[ht][i] + bf;
      VxT[row * Hh + h] = accT[ht][i] + bt;
    }
  }
}

// ---------------------------------------------------------------------------
// Kernel 2: main per-edge kernel (v3).
//   A = weight rows (from XOR-swizzled LDS), B = e rows (global fp32 -> bf16),
//   D: col = edge, row = h  =>  vectorized f32x4 epilogue.
// One wave = 32 edges x 128 h. 8 waves/block (512 thr), VGPR capped at 128
// (launch_bounds(512,4)) -> 2 blocks/CU (64KB LDS) = 16 waves/CU.
// Swizzle: 16B-chunk index within a 256B weight row is XORed with (h&15)
// so each 16-lane b128 phase hits 16 distinct chunks (<=2-way, free).
// ---------------------------------------------------------------------------
__global__ void __launch_bounds__(512, 4) edge_kernel(
    const float* __restrict__ e,
    const int* __restrict__ edge_index,
    const int* __restrict__ inv_edge_index,
    const short* __restrict__ Ubf, const short* __restrict__ iUbf,
    const float* __restrict__ biasA, const float* __restrict__ biasB,
    const float* __restrict__ VxF, const float* __restrict__ VxT,
    float* __restrict__ out) {
  __shared__ short wlds[2 * Hh * Hh];  // 64 KiB: [matrix][h][swizzled chunks]
  // ---- stage U, iU into LDS (4096 chunks of 16B, 512 threads x 8) ----
  #pragma unroll
  for (int it = 0; it < 8; ++it) {
    int idx = it * 512 + (int)threadIdx.x;   // 0..4095
    int m = idx >> 11;                       // matrix
    int rr = idx & 2047;
    int h = rr >> 4, kb = rr & 15;           // row, 16B chunk in row
    const short* src = (m ? iUbf : Ubf) + h * Hh + kb * 8;
    bf16x8 v = *reinterpret_cast<const bf16x8*>(src);
    int dst = m * (Hh * Hh) + h * Hh + ((kb ^ (h & 15)) << 3);
    *reinterpret_cast<bf16x8*>(wlds + dst) = v;
  }
  __syncthreads();

  int wv = (int)((blockIdx.x * blockDim.x + threadIdx.x) >> 6);
  if (wv < Bn * (Ee / 32)) {
    int lane = threadIdx.x & 63;
    int c = lane & 15, kg = lane >> 4;
    constexpr int WPB = Ee / 32;  // 3125
    int b = wv / WPB;
    int j0 = (wv % WPB) * 32;
    const size_t ebase = (size_t)b * Ee;
    const float* ebat = e + ebase * Hh;

    // per-lane edge indices (et = 0,1)
    int jc[2] = {j0 + c, j0 + 16 + c};
    int i2[2], ei[2];
    bool ph[2];
    #pragma unroll
    for (int et = 0; et < 2; ++et) {
      i2[et] = inv_edge_index[ebase + jc[et]];
      ei[et] = edge_index[ebase + jc[et]];
      ph[et] = (i2[et] == Ee);
    }

    f32x4 acc[2][8];
    #pragma unroll
    for (int et = 0; et < 2; ++et)
      #pragma unroll
      for (int ht = 0; ht < 8; ++ht) acc[et][ht] = (f32x4)(0.0f);

    // K loop: per kk load e-fragments (16 VGPRs), then 8 ht tiles from LDS.
    #pragma unroll
    for (int kk = 0; kk < 4; ++kk) {
      int k0 = kk * 32 + kg * 8;
      bf16x8 a1[2], a2[2];
      #pragma unroll
      for (int et = 0; et < 2; ++et) {
        int row2 = ph[et] ? 0 : i2[et];
        a1[et] = cvt8(ebat + (size_t)jc[et] * Hh + k0);
        bf16x8 t = cvt8(ebat + (size_t)row2 * Hh + k0);
        a2[et] = ph[et] ? zero8() : t;
      }
      #pragma unroll
      for (int ht = 0; ht < 8; ++ht) {
        int h = ht * 16 + c;
        int off = h * Hh + ((((kk << 2) + kg) ^ (h & 15)) << 3);
        bf16x8 wu = *reinterpret_cast<const bf16x8*>(wlds + off);
        bf16x8 wi = *reinterpret_cast<const bf16x8*>(wlds + Hh * Hh + off);
        #pragma unroll
        for (int et = 0; et < 2; ++et) {
          acc[et][ht] = __builtin_amdgcn_mfma_f32_16x16x32_bf16(wu, a1[et], acc[et][ht], 0, 0, 0);
          acc[et][ht] = __builtin_amdgcn_mfma_f32_16x16x32_bf16(wi, a2[et], acc[et][ht], 0, 0, 0);
        }
      }
    }

    // Epilogue: D col = edge (lane&15), row = h = ht*16 + kg*4 + i
    #pragma unroll
    for (int et = 0; et < 2; ++et) {
      const float* vt = VxT + ((size_t)b * Nn + ei[et]) * Hh;
      const float* vf = VxF + ((size_t)b * Nn + jc[et] / Kd) * Hh;
      float* orow = out + (ebase + (size_t)jc[et]) * Hh;
      #pragma unroll
      for (int ht = 0; ht < 8; ++ht) {
        int h0 = ht * 16 + kg * 4;
        f32x4 bA = *reinterpret_cast<const f32x4*>(biasA + h0);
        f32x4 bB = *reinterpret_cast<const f32x4*>(biasB + h0);
        f32x4 vt4 = *reinterpret_cast<const f32x4*>(vt + h0);
        f32x4 vf4 = *reinterpret_cast<const f32x4*>(vf + h0);
        f32x4 r = acc[et][ht] + (ph[et] ? bB : bA) + vt4 + vf4;
        *reinterpret_cast<f32x4*>(orow + h0) = r;
      }
    }
  }
}

extern "C" void kernel_launch(void* const* d_in, const int* in_sizes, int n_in,
                              void* d_out, int out_size, void* d_ws, size_t ws_size,
                              hipStream_t stream) {
  const float* x   = (const float*)d_in[0];
  const float* e   = (const float*)d_in[1];
  const int* edge_index = (const int*)d_in[2];
  const int* inv_edge_index = (const int*)d_in[3];
  const float* U_w  = (const float*)d_in[4];
  const float* U_b  = (const float*)d_in[5];
  const float* Vf_w = (const float*)d_in[6];
  const float* Vf_b = (const float*)d_in[7];
  const float* Vt_w = (const float*)d_in[8];
  const float* Vt_b = (const float*)d_in[9];
  const float* iU_w = (const float*)d_in[10];
  const float* iU_b = (const float*)d_in[11];
  const float* W_ph = (const float*)d_in[12];
  float* out = (float*)d_out;

  // Workspace layout
  float* VxF   = (float*)d_ws;                         // B*N*H floats
  float* VxT   = VxF + (size_t)Bn * Nn * Hh;           // B*N*H floats
  float* biasA = VxT + (size_t)Bn * Nn * Hh;           // 128
  float* biasB = biasA + Hh;                           // 128
  short* Ubf   = (short*)(biasB + Hh);                 // 16384 shorts
  short* iUbf  = Ubf + Hh * Hh;
  short* Vfbf  = iUbf + Hh * Hh;
  short* Vtbf  = Vfbf + Hh * Hh;

  prep_kernel<<<dim3(64), dim3(256), 0, stream>>>(
      U_w, iU_w, Vf_w, Vt_w, U_b, iU_b, W_ph, Ubf, iUbf, Vfbf, Vtbf, biasA, biasB);

  vxproj_kernel<<<dim3(313), dim3(256), 0, stream>>>(
      x, Vfbf, Vtbf, Vf_b, Vt_b, VxF, VxT);

  int nwaves = Bn * (Ee / 32);                 // 12500
  int nblocks = (nwaves + 7) / 8;              // 1563 blocks of 512 threads
  edge_kernel<<<dim3(nblocks), dim3(512), 0, stream>>>(
      e, edge_index, inv_edge_index, Ubf, iUbf, biasA, biasB, VxF, VxT, out);
}